// Round 1
// baseline (296.428 us; speedup 1.0000x reference)
//
#include <hip/hip_runtime.h>
#include <hip/hip_bf16.h>

// 1-NN VQ: x [M=131072][C=128] fp32, codebook [K=256][C=128] fp32 -> int32 idx[M]
// argmin_k (c_sq[k] - 2*q.c_k)  (q_sq constant per row, dropped)
//
// Block = 256 threads (one per code k). Each block handles QB=64 queries.
// Query tile staged in LDS (broadcast reads in inner loop -> conflict-free).
// Epilogue: scores -> LDS (stride 257), 4-thread/query scan with u64 key
// (monotonic float bits << 32 | k) so min == (min score, lowest k).

#define QB 64
#define C 128
#define K 256

__device__ __forceinline__ unsigned fmap(float f) {
    unsigned u = __float_as_uint(f);
    return (u & 0x80000000u) ? ~u : (u | 0x80000000u);
}

__global__ __launch_bounds__(256) void knn_kernel(const float* __restrict__ x,
                                                  const float* __restrict__ cb,
                                                  int* __restrict__ out) {
    // LDS: phase 1 = query tile QB*C floats (8192 = 32 KB)
    //      phase 2 = score matrix QB rows * stride 257 (16448 floats = 64.25 KB)
    __shared__ float S[QB * 257];

    const int tid = threadIdx.x;          // == code index k
    const int k = tid;

    // ---- stage query tile (coalesced float4) ----
    const float4* xin4 = (const float4*)(x + (size_t)blockIdx.x * (QB * C));
    float4* q4 = (float4*)S;
#pragma unroll
    for (int i = 0; i < (QB * C / 4) / 256; ++i) {   // 8 iters
        q4[i * 256 + tid] = xin4[i * 256 + tid];
    }
    __syncthreads();

    // ---- main loop: dot(q, code_k) for 64 queries ----
    float acc[QB];
#pragma unroll
    for (int q = 0; q < QB; ++q) acc[q] = 0.0f;

    const float4* cbrow = (const float4*)(cb + (size_t)k * C);
    float csq = 0.0f;

    float4 cc = cbrow[0];
    for (int c4 = 0; c4 < C / 4; ++c4) {
        float4 nxt;
        if (c4 < C / 4 - 1) nxt = cbrow[c4 + 1];
        else { nxt.x = 0.f; nxt.y = 0.f; nxt.z = 0.f; nxt.w = 0.f; }

        csq = fmaf(cc.x, cc.x, csq);
        csq = fmaf(cc.y, cc.y, csq);
        csq = fmaf(cc.z, cc.z, csq);
        csq = fmaf(cc.w, cc.w, csq);

        const float* qbase = S + c4 * 4;
#pragma unroll
        for (int q = 0; q < QB; ++q) {
            float4 qq = *(const float4*)(qbase + q * C);   // ds_read_b128, broadcast
            float a = acc[q];
            a = fmaf(cc.x, qq.x, a);
            a = fmaf(cc.y, qq.y, a);
            a = fmaf(cc.z, qq.z, a);
            a = fmaf(cc.w, qq.w, a);
            acc[q] = a;
        }
        cc = nxt;
    }

    __syncthreads();   // all Q reads done before overwrite with scores

    // ---- write scores: score[q][k] = c_sq - 2*dot ----
#pragma unroll
    for (int q = 0; q < QB; ++q) {
        S[q * 257 + k] = fmaf(-2.0f, acc[q], csq);
    }
    __syncthreads();

    // ---- argmin scan: 4 threads per query, 64 codes each ----
    const int q = tid >> 2;
    const int part = tid & 3;
    const float* row = S + q * 257 + part * 64;

    unsigned long long best = ~0ULL;
#pragma unroll 8
    for (int i = 0; i < 64; ++i) {
        unsigned u = fmap(row[i]);
        unsigned long long key =
            ((unsigned long long)u << 32) | (unsigned)(part * 64 + i);
        best = key < best ? key : best;
    }
    {
        unsigned long long o = __shfl_xor(best, 1);
        best = o < best ? o : best;
        o = __shfl_xor(best, 2);
        best = o < best ? o : best;
    }
    if (part == 0) {
        out[(size_t)blockIdx.x * QB + q] = (int)(unsigned)(best & 0xFFFFFFFFull);
    }
}

extern "C" void kernel_launch(void* const* d_in, const int* in_sizes, int n_in,
                              void* d_out, int out_size, void* d_ws, size_t ws_size,
                              hipStream_t stream) {
    const float* x = (const float*)d_in[0];
    const float* cb = (const float*)d_in[1];
    int* out = (int*)d_out;

    const int M = in_sizes[0] / C;       // 131072
    dim3 grid(M / QB);                   // 2048 blocks
    knn_kernel<<<grid, 256, 0, stream>>>(x, cb, out);
}